// Round 5
// baseline (1034.287 us; speedup 1.0000x reference)
//
#include <hip/hip_runtime.h>
#include <hip/hip_bf16.h>
#include <stdint.h>

// BitLinear: out[m][n] = scale[n] * sum_k x[m][k] * q[n][k], q ternary.
// M = B*S = 8192, K = 2048, N = 8192.
// ABLATION ROUND: V3 (pure MFMA), V1 (no ds_reads), V2 (no staging), then
// V0 (real kernel, unchanged, runs LAST and overwrites all of out).
// V1/V2/V3 sink their acc into out[...] which V0 later overwrites fully.

typedef float  floatx4 __attribute__((ext_vector_type(4)));
typedef _Float16 f16x8 __attribute__((ext_vector_type(8)));
typedef _Float16 f16x4 __attribute__((ext_vector_type(4)));

#define BM 256
#define BN 256
#define BK 32
#define NSLOT 4

// ---------------- Kernel 1: per-row scale + ternary quantize to fp16 --------
__global__ __launch_bounds__(256) void quant_weight(
    const float* __restrict__ W, f16x4* __restrict__ Q,
    float* __restrict__ scale, int K /*2048*/)
{
    const int wave = threadIdx.x >> 6;
    const int lane = threadIdx.x & 63;
    const int row  = blockIdx.x * 4 + wave;

    const float4* row4 = (const float4*)(W + (size_t)row * K);  // 512 float4
    float4 v[8];
    float s = 0.f;
    #pragma unroll
    for (int i = 0; i < 8; ++i) {
        v[i] = row4[lane + 64 * i];
        s += fabsf(v[i].x) + fabsf(v[i].y) + fabsf(v[i].z) + fabsf(v[i].w);
    }
    #pragma unroll
    for (int m = 1; m < 64; m <<= 1) s += __shfl_xor(s, m, 64);

    const float sc  = fmaxf(s / (float)K, 1e-5f);
    if (lane == 0) scale[row] = sc;
    const float inv = 1.0f / sc;

    f16x4* qrow = Q + (size_t)row * (K / 4);
    #pragma unroll
    for (int i = 0; i < 8; ++i) {
        float t[4] = {v[i].x, v[i].y, v[i].z, v[i].w};
        f16x4 o;
        #pragma unroll
        for (int j = 0; j < 4; ++j)
            o[j] = (_Float16)fminf(fmaxf(rintf(t[j] * inv), -1.f), 1.f);
        qrow[lane + 64 * i] = o;
    }
}

// ---------------- Kernel 2: x fp32 -> fp16 (RNE) ----------------------------
__global__ __launch_bounds__(256) void cvt_f16(
    const float4* __restrict__ X, f16x4* __restrict__ Y)
{
    const size_t i = (size_t)blockIdx.x * blockDim.x + threadIdx.x;
    float4 a = X[i];
    f16x4 o;
    o[0] = (_Float16)a.x; o[1] = (_Float16)a.y;
    o[2] = (_Float16)a.z; o[3] = (_Float16)a.w;
    Y[i] = o;
}

__device__ inline void gload_lds16(const void* g, void* l) {
    __builtin_amdgcn_global_load_lds(
        (const __attribute__((address_space(1))) void*)g,
        (__attribute__((address_space(3))) void*)l, 16, 0, 0);
}

// Common per-block setup macro (same in every variant).
#define GEMM_SETUP                                                           \
    __shared__ __align__(16) _Float16 lds[NSLOT][2][BM * BK];                \
    const int tid  = threadIdx.x;                                            \
    const int lane = tid & 63;                                               \
    const int wv   = tid >> 6;                                               \
    const int wm   = wv >> 2;                                                \
    const int wn   = wv & 3;                                                 \
    const int nwg = gridDim.x;                                               \
    const int cpx = nwg >> 3;                                                \
    const int id  = blockIdx.x;                                              \
    const int j   = (id >> 3) + (id & 7) * cpx;                              \
    const int nbx = N / BN;                                                  \
    const int per_band = nbx * 8;                                            \
    const int band = j / per_band;                                           \
    const int jj   = j % per_band;                                           \
    const int bx   = jj >> 3;                                                \
    const int by   = band * 8 + (jj & 7);                                    \
    const int rowA0 = by * BM;                                               \
    const int rowB0 = bx * BN;                                               \
    const int lrow  = lane & 15;                                             \
    const int kquad = lane >> 4;                                             \
    floatx4 acc[8][4] = {};                                                  \
    int aoff[8], boff[4];                                                    \
    _Pragma("unroll")                                                        \
    for (int t = 0; t < 8; ++t) {                                            \
        int ra = wm * 128 + t * 16 + lrow;                                   \
        aoff[t] = (ra * 4 + (kquad ^ ((ra >> 1) & 3))) * 8;                  \
    }                                                                        \
    _Pragma("unroll")                                                        \
    for (int t = 0; t < 4; ++t) {                                            \
        int rb = wn * 64 + t * 16 + lrow;                                    \
        boff[t] = (rb * 4 + (kquad ^ ((rb >> 1) & 3))) * 8;                  \
    }                                                                        \
    const int c0 = tid,        c1 = tid + 512;                               \
    const int r0 = c0 >> 2,    r1 = c1 >> 2;                                 \
    const int k0 = (c0 & 3) ^ ((r0 >> 1) & 3);                               \
    const int k1 = (c1 & 3) ^ ((r1 >> 1) & 3);                               \
    const _Float16* pa0 = A + (size_t)(rowA0 + r0) * K + k0 * 8;             \
    const _Float16* pa1 = A + (size_t)(rowA0 + r1) * K + k1 * 8;             \
    const _Float16* pb0 = B + (size_t)(rowB0 + r0) * K + k0 * 8;             \
    const _Float16* pb1 = B + (size_t)(rowB0 + r1) * K + k1 * 8;             \
    const int eo0 = c0 * 8, eo1 = c1 * 8;

// Sink: sum all acc lanes so no MFMA is dead (rule 17), one write/thread.
#define GEMM_SINK(OUT)                                                       \
    {                                                                        \
        float snk = 0.f;                                                     \
        _Pragma("unroll")                                                    \
        for (int mt = 0; mt < 8; ++mt)                                       \
            _Pragma("unroll")                                                \
            for (int nt = 0; nt < 4; ++nt)                                   \
                _Pragma("unroll")                                            \
                for (int r = 0; r < 4; ++r) snk += acc[mt][nt][r];           \
        OUT[(size_t)blockIdx.x * 512 + tid] = snk;                           \
    }

// ---------------- V3: pure MFMA loop (in-situ pipe ceiling) -----------------
__global__ __launch_bounds__(512, 2) void gemm_v3_mfma_only(
    const _Float16* __restrict__ A, const _Float16* __restrict__ B,
    const float* __restrict__ scale, float* __restrict__ C,
    int M, int N, int K)
{
    GEMM_SETUP
    (void)pa1; (void)pb1; (void)eo1; (void)scale;
    // stage tile 0 once so frags hold real data
    gload_lds16(pa0, &lds[0][0][eo0]);
    gload_lds16(pa0 + (size_t)0, &lds[0][0][eo1]);   // duplicate src, fills eo1
    gload_lds16(pb0, &lds[0][1][eo0]);
    gload_lds16(pb0 + (size_t)0, &lds[0][1][eo1]);
    asm volatile("s_waitcnt vmcnt(0)" ::: "memory");
    __builtin_amdgcn_s_barrier();
    f16x8 bfr[4], afrA[4], afrB[4];
    #pragma unroll
    for (int t = 0; t < 4; ++t) bfr[t]  = *(const f16x8*)&lds[0][1][boff[t]];
    #pragma unroll
    for (int t = 0; t < 4; ++t) afrA[t] = *(const f16x8*)&lds[0][0][aoff[t]];
    #pragma unroll
    for (int t = 0; t < 4; ++t) afrB[t] = *(const f16x8*)&lds[0][0][aoff[t + 4]];
    asm volatile("s_waitcnt lgkmcnt(0)" ::: "memory");

    const int NT = K / BK;   // 64 iterations, 32 MFMA each
    for (int kt = 0; kt < NT; ++kt) {
        __builtin_amdgcn_s_setprio(1);
        #pragma unroll
        for (int mt = 0; mt < 4; ++mt)
            #pragma unroll
            for (int nt = 0; nt < 4; ++nt)
                acc[mt][nt] = __builtin_amdgcn_mfma_f32_16x16x32_f16(
                    afrA[mt], bfr[nt], acc[mt][nt], 0, 0, 0);
        #pragma unroll
        for (int mt = 0; mt < 4; ++mt)
            #pragma unroll
            for (int nt = 0; nt < 4; ++nt)
                acc[mt + 4][nt] = __builtin_amdgcn_mfma_f32_16x16x32_f16(
                    afrB[mt], bfr[nt], acc[mt + 4][nt], 0, 0, 0);
        __builtin_amdgcn_s_setprio(0);
    }
    GEMM_SINK(C)
}

// ---------------- V1: full schedule MINUS ds_reads --------------------------
__global__ __launch_bounds__(512, 2) void gemm_v1_no_dsread(
    const _Float16* __restrict__ A, const _Float16* __restrict__ B,
    const float* __restrict__ scale, float* __restrict__ C,
    int M, int N, int K)
{
    GEMM_SETUP
    (void)scale;
    // prologue: stage tiles 0..2 (12 loads/thread) -- identical to V0
    #pragma unroll
    for (int t = 0; t < 3; ++t) {
        gload_lds16(pa0 + t * BK, &lds[t][0][eo0]);
        gload_lds16(pa1 + t * BK, &lds[t][0][eo1]);
        gload_lds16(pb0 + t * BK, &lds[t][1][eo0]);
        gload_lds16(pb1 + t * BK, &lds[t][1][eo1]);
    }
    pa0 += 3 * BK; pa1 += 3 * BK; pb0 += 3 * BK; pb1 += 3 * BK;
    asm volatile("s_waitcnt vmcnt(8)" ::: "memory");
    __builtin_amdgcn_s_barrier();

    // fixed fragments (read once; never re-read in the loop)
    f16x8 bfr[4], afrA[4], afrB[4];
    #pragma unroll
    for (int t = 0; t < 4; ++t) bfr[t]  = *(const f16x8*)&lds[0][1][boff[t]];
    #pragma unroll
    for (int t = 0; t < 4; ++t) afrA[t] = *(const f16x8*)&lds[0][0][aoff[t]];
    #pragma unroll
    for (int t = 0; t < 4; ++t) afrB[t] = *(const f16x8*)&lds[0][0][aoff[t + 4]];
    asm volatile("s_waitcnt lgkmcnt(0)" ::: "memory");
    __builtin_amdgcn_sched_barrier(0);

    const int NT = K / BK;
    for (int kt0 = 0; kt0 < NT; kt0 += NSLOT) {
        #pragma unroll
        for (int S = 0; S < NSLOT; ++S) {
            const int kt = kt0 + S;
            const int d  = (S + 3) & 3;
            // phase A: stage all of tile kt+3 (same as V0), NO frag reads
            if (kt + 3 < NT) {
                gload_lds16(pa0, &lds[d][0][eo0]);
                gload_lds16(pa1, &lds[d][0][eo1]);
                gload_lds16(pb0, &lds[d][1][eo0]);
                gload_lds16(pb1, &lds[d][1][eo1]);
                pa0 += BK; pa1 += BK; pb0 += BK; pb1 += BK;
            }
            __builtin_amdgcn_sched_barrier(0);
            __builtin_amdgcn_s_setprio(1);
            #pragma unroll
            for (int mt = 0; mt < 4; ++mt)
                #pragma unroll
                for (int nt = 0; nt < 4; ++nt)
                    acc[mt][nt] = __builtin_amdgcn_mfma_f32_16x16x32_f16(
                        afrA[mt], bfr[nt], acc[mt][nt], 0, 0, 0);
            __builtin_amdgcn_s_setprio(0);
            __builtin_amdgcn_sched_barrier(0);
            asm volatile("s_waitcnt vmcnt(8)" ::: "memory");
            __builtin_amdgcn_s_barrier();        // MID
            __builtin_amdgcn_sched_barrier(0);
            // phase B
            __builtin_amdgcn_s_setprio(1);
            #pragma unroll
            for (int mt = 0; mt < 4; ++mt)
                #pragma unroll
                for (int nt = 0; nt < 4; ++nt)
                    acc[mt + 4][nt] = __builtin_amdgcn_mfma_f32_16x16x32_f16(
                        afrB[mt], bfr[nt], acc[mt + 4][nt], 0, 0, 0);
            __builtin_amdgcn_s_setprio(0);
            __builtin_amdgcn_sched_barrier(0);
            __builtin_amdgcn_s_barrier();        // BOUNDARY
            __builtin_amdgcn_sched_barrier(0);
        }
    }
    GEMM_SINK(C)
}

// ---------------- V2: full schedule MINUS staging/vmcnt ---------------------
__global__ __launch_bounds__(512, 2) void gemm_v2_no_stage(
    const _Float16* __restrict__ A, const _Float16* __restrict__ B,
    const float* __restrict__ scale, float* __restrict__ C,
    int M, int N, int K)
{
    GEMM_SETUP
    (void)scale;
    // prologue: stage ALL 4 slots once (16 loads/thread), then never again
    #pragma unroll
    for (int t = 0; t < 4; ++t) {
        gload_lds16(pa0 + t * BK, &lds[t][0][eo0]);
        gload_lds16(pa1 + t * BK, &lds[t][0][eo1]);
        gload_lds16(pb0 + t * BK, &lds[t][1][eo0]);
        gload_lds16(pb1 + t * BK, &lds[t][1][eo1]);
    }
    asm volatile("s_waitcnt vmcnt(0)" ::: "memory");
    __builtin_amdgcn_s_barrier();
    __builtin_amdgcn_sched_barrier(0);

    const int NT = K / BK;
    f16x8 bfrE[4], bfrO[4], afrA[4], afrB[4];
    #pragma unroll
    for (int t = 0; t < 4; ++t) bfrE[t] = *(const f16x8*)&lds[0][1][boff[t]];
    #pragma unroll
    for (int t = 0; t < 4; ++t) afrA[t] = *(const f16x8*)&lds[0][0][aoff[t]];

#define TILE_STEP_V2(S, BCUR, BNXT)                                          \
    {                                                                        \
        const int kt = kt0 + S;                                              \
        const int sn = (S + 1) & 3;                                          \
        afrB[0] = *(const f16x8*)&lds[S][0][aoff[4]];                        \
        afrB[1] = *(const f16x8*)&lds[S][0][aoff[5]];                        \
        afrB[2] = *(const f16x8*)&lds[S][0][aoff[6]];                        \
        afrB[3] = *(const f16x8*)&lds[S][0][aoff[7]];                        \
        asm volatile("s_waitcnt lgkmcnt(4)" ::: "memory");                   \
        __builtin_amdgcn_sched_barrier(0);                                   \
        __builtin_amdgcn_s_setprio(1);                                       \
        _Pragma("unroll")                                                    \
        for (int mt = 0; mt < 4; ++mt)                                       \
            _Pragma("unroll")                                                \
            for (int nt = 0; nt < 4; ++nt)                                   \
                acc[mt][nt] = __builtin_amdgcn_mfma_f32_16x16x32_f16(        \
                    afrA[mt], BCUR[nt], acc[mt][nt], 0, 0, 0);               \
        __builtin_amdgcn_s_setprio(0);                                       \
        __builtin_amdgcn_sched_barrier(0);                                   \
        __builtin_amdgcn_s_barrier();        /* MID */                       \
        __builtin_amdgcn_sched_barrier(0);                                   \
        if (kt + 1 < NT) {                                                   \
            BNXT[0] = *(const f16x8*)&lds[sn][1][boff[0]];                   \
            BNXT[1] = *(const f16x8*)&lds[sn][1][boff[1]];                   \
            BNXT[2] = *(const f16x8*)&lds[sn][1][boff[2]];                   \
            BNXT[3] = *(const f16x8*)&lds[sn][1][boff[3]];                   \
            afrA[0] = *(const f16x8*)&lds[sn][0][aoff[0]];                   \
            afrA[1] = *(const f16x8*)&lds[sn][0][aoff[1]];                   \
            afrA[2] = *(const f16x8*)&lds[sn][0][aoff[2]];                   \
            afrA[3] = *(const f16x8*)&lds[sn][0][aoff[3]];                   \
            asm volatile("s_waitcnt lgkmcnt(8)" ::: "memory");               \
        } else {                                                             \
            asm volatile("s_waitcnt lgkmcnt(0)" ::: "memory");               \
        }                                                                    \
        __builtin_amdgcn_sched_barrier(0);                                   \
        __builtin_amdgcn_s_setprio(1);                                       \
        _Pragma("unroll")                                                    \
        for (int mt = 0; mt < 4; ++mt)                                       \
            _Pragma("unroll")                                                \
            for (int nt = 0; nt < 4; ++nt)                                   \
                acc[mt + 4][nt] = __builtin_amdgcn_mfma_f32_16x16x32_f16(    \
                    afrB[mt], BCUR[nt], acc[mt + 4][nt], 0, 0, 0);           \
        __builtin_amdgcn_s_setprio(0);                                       \
        __builtin_amdgcn_sched_barrier(0);                                   \
        __builtin_amdgcn_s_barrier();        /* BOUNDARY */                  \
        __builtin_amdgcn_sched_barrier(0);                                   \
    }

    for (int kt0 = 0; kt0 < NT; kt0 += NSLOT) {
        TILE_STEP_V2(0, bfrE, bfrO)
        TILE_STEP_V2(1, bfrO, bfrE)
        TILE_STEP_V2(2, bfrE, bfrO)
        TILE_STEP_V2(3, bfrO, bfrE)
    }
#undef TILE_STEP_V2
    GEMM_SINK(C)
}

// ---------------- V0: real kernel (unchanged from round 4) ------------------
__global__ __launch_bounds__(512, 2) void gemm_bt_scaled(
    const _Float16* __restrict__ A,   // [M,K]
    const _Float16* __restrict__ B,   // [N,K] ternary
    const float* __restrict__ scale,  // [N]
    float* __restrict__ C,            // [M,N]
    int M, int N, int K)
{
    GEMM_SETUP

    // prologue: stage tiles 0..2 into slots 0..2 (12 loads/thread)
    #pragma unroll
    for (int t = 0; t < 3; ++t) {
        gload_lds16(pa0 + t * BK, &lds[t][0][eo0]);
        gload_lds16(pa1 + t * BK, &lds[t][0][eo1]);
        gload_lds16(pb0 + t * BK, &lds[t][1][eo0]);
        gload_lds16(pb1 + t * BK, &lds[t][1][eo1]);
    }
    pa0 += 3 * BK; pa1 += 3 * BK; pb0 += 3 * BK; pb1 += 3 * BK;

    asm volatile("s_waitcnt vmcnt(8)" ::: "memory"); // tile 0 landed
    __builtin_amdgcn_s_barrier();
    __builtin_amdgcn_sched_barrier(0);

    const int NT = K / BK;   // 64

    f16x8 bfrE[4], bfrO[4], afrA[4], afrB[4];
    #pragma unroll
    for (int t = 0; t < 4; ++t) bfrE[t] = *(const f16x8*)&lds[0][1][boff[t]];
    #pragma unroll
    for (int t = 0; t < 4; ++t) afrA[t] = *(const f16x8*)&lds[0][0][aoff[t]];

#define TILE_STEP(S, BCUR, BNXT)                                             \
    {                                                                        \
        const int kt = kt0 + S;                                              \
        const int d  = (S + 3) & 3;                                          \
        const int sn = (S + 1) & 3;                                          \
        if (kt + 3 < NT) {                                                   \
            gload_lds16(pa0, &lds[d][0][eo0]);                               \
            gload_lds16(pa1, &lds[d][0][eo1]);                               \
            gload_lds16(pb0, &lds[d][1][eo0]);                               \
            gload_lds16(pb1, &lds[d][1][eo1]);                               \
            pa0 += BK; pa1 += BK; pb0 += BK; pb1 += BK;                      \
        }                                                                    \
        afrB[0] = *(const f16x8*)&lds[S][0][aoff[4]];                        \
        afrB[1] = *(const f16x8*)&lds[S][0][aoff[5]];                        \
        afrB[2] = *(const f16x8*)&lds[S][0][aoff[6]];                        \
        afrB[3] = *(const f16x8*)&lds[S][0][aoff[7]];                        \
        asm volatile("s_waitcnt lgkmcnt(4)" ::: "memory");                   \
        __builtin_amdgcn_sched_barrier(0);                                   \
        __builtin_amdgcn_s_setprio(1);                                       \
        _Pragma("unroll")                                                    \
        for (int mt = 0; mt < 4; ++mt)                                       \
            _Pragma("unroll")                                                \
            for (int nt = 0; nt < 4; ++nt)                                   \
                acc[mt][nt] = __builtin_amdgcn_mfma_f32_16x16x32_f16(        \
                    afrA[mt], BCUR[nt], acc[mt][nt], 0, 0, 0);               \
        __builtin_amdgcn_s_setprio(0);                                       \
        __builtin_amdgcn_sched_barrier(0);                                   \
        asm volatile("s_waitcnt vmcnt(8)" ::: "memory");                     \
        __builtin_amdgcn_s_barrier();        /* MID barrier */               \
        __builtin_amdgcn_sched_barrier(0);                                   \
        if (kt + 1 < NT) {                                                   \
            BNXT[0] = *(const f16x8*)&lds[sn][1][boff[0]];                   \
            BNXT[1] = *(const f16x8*)&lds[sn][1][boff[1]];                   \
            BNXT[2] = *(const f16x8*)&lds[sn][1][boff[2]];                   \
            BNXT[3] = *(const f16x8*)&lds[sn][1][boff[3]];                   \
            afrA[0] = *(const f16x8*)&lds[sn][0][aoff[0]];                   \
            afrA[1] = *(const f16x8*)&lds[sn][0][aoff[1]];                   \
            afrA[2] = *(const f16x8*)&lds[sn][0][aoff[2]];                   \
            afrA[3] = *(const f16x8*)&lds[sn][0][aoff[3]];                   \
            asm volatile("s_waitcnt lgkmcnt(8)" ::: "memory");               \
        } else {                                                             \
            asm volatile("s_waitcnt lgkmcnt(0)" ::: "memory");               \
        }                                                                    \
        __builtin_amdgcn_sched_barrier(0);                                   \
        __builtin_amdgcn_s_setprio(1);                                       \
        _Pragma("unroll")                                                    \
        for (int mt = 0; mt < 4; ++mt)                                       \
            _Pragma("unroll")                                                \
            for (int nt = 0; nt < 4; ++nt)                                   \
                acc[mt + 4][nt] = __builtin_amdgcn_mfma_f32_16x16x32_f16(    \
                    afrB[mt], BCUR[nt], acc[mt + 4][nt], 0, 0, 0);           \
        __builtin_amdgcn_s_setprio(0);                                       \
        __builtin_amdgcn_sched_barrier(0);                                   \
        __builtin_amdgcn_s_barrier();        /* BOUNDARY barrier */          \
        __builtin_amdgcn_sched_barrier(0);                                   \
    }

    for (int kt0 = 0; kt0 < NT; kt0 += NSLOT) {
        TILE_STEP(0, bfrE, bfrO)
        TILE_STEP(1, bfrO, bfrE)
        TILE_STEP(2, bfrE, bfrO)
        TILE_STEP(3, bfrO, bfrE)
    }
#undef TILE_STEP

    // epilogue: D mapping col = lane&15 (n), row = (lane>>4)*4 + reg (m)
    const int colb = rowB0 + wn * 64 + lrow;
    const int rowb = rowA0 + wm * 128 + kquad * 4;
    #pragma unroll
    for (int nt = 0; nt < 4; ++nt) {
        const float sc = scale[colb + nt * 16];
        #pragma unroll
        for (int mt = 0; mt < 8; ++mt) {
            #pragma unroll
            for (int r = 0; r < 4; ++r) {
                C[(size_t)(rowb + mt * 16 + r) * N + colb + nt * 16] =
                    acc[mt][nt][r] * sc;
            }
        }
    }
}

extern "C" void kernel_launch(void* const* d_in, const int* in_sizes, int n_in,
                              void* d_out, int out_size, void* d_ws, size_t ws_size,
                              hipStream_t stream) {
    const float* x = (const float*)d_in[0];      // [4,2048,2048] fp32
    const float* w = (const float*)d_in[1];      // [8192,2048] fp32
    float* out = (float*)d_out;                  // [4,2048,8192] fp32

    const int M = 8192, K = 2048, N = 8192;

    char* ws = (char*)d_ws;
    float*     scale = (float*)ws;                                 // 32 KiB
    _Float16*  Xh    = (_Float16*)(ws + 32768);                    // 32 MiB
    _Float16*  Qh    = (_Float16*)(ws + 32768 + (size_t)M * K * 2);// 32 MiB

    quant_weight<<<N / 4, 256, 0, stream>>>(w, (f16x4*)Qh, scale, K);
    cvt_f16<<<(M * K / 4) / 256, 256, 0, stream>>>((const float4*)x, (f16x4*)Xh);

    // diagnostics (sink-writes into out; V0 below overwrites everything)
    gemm_v3_mfma_only<<<dim3((M / BM) * (N / BN)), 512, 0, stream>>>(
        Xh, Qh, scale, out, M, N, K);
    gemm_v1_no_dsread<<<dim3((M / BM) * (N / BN)), 512, 0, stream>>>(
        Xh, Qh, scale, out, M, N, K);
    gemm_v2_no_stage<<<dim3((M / BM) * (N / BN)), 512, 0, stream>>>(
        Xh, Qh, scale, out, M, N, K);

    // real kernel LAST: writes the full output
    gemm_bt_scaled<<<dim3((M / BM) * (N / BN)), 512, 0, stream>>>(
        Xh, Qh, scale, out, M, N, K);
}